// Round 11
// baseline (140.113 us; speedup 1.0000x reference)
//
#include <hip/hip_runtime.h>
#include <hip/hip_bf16.h>
#include <cstdint>
#include <cstddef>

#define VOCAB 32000
#define HIDDEN 2048
#define NLAYERS 6
#define BATCH 512

#define BM 64
#define BN 64
#define BK 64
#define SPLITK 4
#define KC (HIDDEN / SPLITK)  // 512 K per block
#define NT (KC / BK)          // 8 K-tiles
#define GEMM_BLOCKS 1024
#define TRANS_BLOCKS 1024
#define CVT_BLOCKS 1024
#define NTILES 256            // (512/64)*(2048/64)
#define MN ((size_t)BATCH * HIDDEN)

typedef __attribute__((ext_vector_type(8))) short bf16x8;
typedef __attribute__((ext_vector_type(4))) float f32x4;

__device__ __forceinline__ unsigned short f2bf(float f) {
  unsigned u = __builtin_bit_cast(unsigned, f);
  u += 0x7fffu + ((u >> 16) & 1u);  // RNE
  return (unsigned short)(u >> 16);
}

__device__ __forceinline__ float tanh_fast(float x) {
  x = fminf(15.f, fmaxf(-15.f, x));
  float e = __expf(2.f * x);
  return (e - 1.f) / (e + 1.f);
}

__device__ __forceinline__ void gload_lds16(const void* g, void* l) {
  __builtin_amdgcn_global_load_lds(
      (const __attribute__((address_space(1))) void*)g,
      (__attribute__((address_space(3))) void*)l, 16, 0, 0);
}

// ---- shared transpose tile body: hh fp32 [K][N] 64x64 tile -> bt bf16 [N][K] ----
__device__ __forceinline__ void transpose_tile(const float* __restrict__ src_layer,
                                               unsigned short* __restrict__ dst_layer,
                                               int n0, int k0, int t,
                                               unsigned short (*tile)[72]) {
  const float* src = src_layer + (size_t)k0 * HIDDEN + n0;
  const int cr = t >> 4;        // 0..15
  const int cc = (t & 15) * 4;  // 0..60
#pragma unroll
  for (int p = 0; p < 4; ++p) {
    const int r = p * 16 + cr;
    float4 v = *(const float4*)(src + (size_t)r * HIDDEN + cc);
    tile[r][cc + 0] = f2bf(v.x);
    tile[r][cc + 1] = f2bf(v.y);
    tile[r][cc + 2] = f2bf(v.z);
    tile[r][cc + 3] = f2bf(v.w);
  }
  __syncthreads();
  const int nl = t >> 2;        // output row (n), 0..63
  const int kk = (t & 3) * 16;  // k chunk
  unsigned short tmp[16] __attribute__((aligned(16)));
#pragma unroll
  for (int j = 0; j < 16; ++j) tmp[j] = tile[kk + j][nl];
  unsigned short* dst = dst_layer + (size_t)(n0 + nl) * HIDDEN + k0 + kk;
  *(uint4*)(dst) = *(const uint4*)(tmp);
  *(uint4*)(dst + 8) = *(const uint4*)(tmp + 8);
}

// ---- prep0: transpose layer 0 + cvt initial state + zero split-K counters ----
__global__ __launch_bounds__(256) void k_prep0(const float* __restrict__ hh0,
                                               unsigned short* __restrict__ bt0,
                                               const float* __restrict__ state,
                                               unsigned short* __restrict__ stb,
                                               unsigned* __restrict__ cnt) {
  __shared__ unsigned short tile[64][72];
  const int wg = blockIdx.x;
  const int t = threadIdx.x;
  if (wg < TRANS_BLOCKS) {
    transpose_tile(hh0, bt0, (wg & 31) * 64, (wg >> 5) * 64, t, tile);
    return;
  }
  if (wg < TRANS_BLOCKS + CVT_BLOCKS) {
    const int i = ((wg - TRANS_BLOCKS) * 256 + t) * 4;
    float4 v = *(const float4*)(state + i);
    union { unsigned short h[4]; uint2 u; } o;
    o.h[0] = f2bf(v.x); o.h[1] = f2bf(v.y); o.h[2] = f2bf(v.z); o.h[3] = f2bf(v.w);
    *(uint2*)(stb + i) = o.u;
    return;
  }
  // zero split-K counters (replay-safe: re-zeroed every kernel_launch)
  cnt[(wg - TRANS_BLOCKS - CVT_BLOCKS) * 256 + t] = 0u;
}

// ---- fused layer: blocks 0..1023 = split-K GEMM (+last-block epilogue);
//      blocks 1024..2047 = transpose of layer l+1 (absent for last layer) ----
__global__ __launch_bounds__(256, 4) void k_layer(
    const unsigned short* __restrict__ A, const unsigned short* __restrict__ Bt,
    float* __restrict__ part, unsigned* __restrict__ cnt,
    const float* __restrict__ prev, const float* __restrict__ ihl,
    const int* __restrict__ token, float* __restrict__ outf,
    unsigned short* __restrict__ outb,
    const float* __restrict__ hhNext, unsigned short* __restrict__ btNext) {
  __shared__ __attribute__((aligned(16))) unsigned char smem[32768];
  __shared__ unsigned s_old;
  const int t = threadIdx.x;
  const int wg = blockIdx.x;

  if (wg >= GEMM_BLOCKS) {
    const int tn = wg - GEMM_BLOCKS;
    transpose_tile(hhNext, btNext, (tn & 31) * 64, (tn >> 5) * 64, t,
                   (unsigned short(*)[72])smem);
    return;
  }

  unsigned short (*As)[BM][BK] = (unsigned short(*)[BM][BK])smem;            // [2]
  unsigned short (*Bs)[BN][BK] = (unsigned short(*)[BN][BK])(smem + 16384);  // [2]

  // XCD-grouped mapping (r8): all 4 kz blocks of a tile share wg&7.
  const int xcd = wg & 7;
  const int idx = wg >> 3;
  const int pnl = xcd * 4 + (idx & 3);  // n-panel 0..31
  const int mt = (idx >> 2) & 7;        // m-tile 0..7
  const int kz = idx >> 5;              // 0..3
  const int n0 = pnl * BN;
  const int m0 = mt * BM;
  const int kbase = kz * KC;
  const int lane = t & 63;
  const int wid = t >> 6;
  const int wm = (wid >> 1) * 32;
  const int wn = (wid & 1) * 32;

  f32x4 zero = {0.f, 0.f, 0.f, 0.f};
  f32x4 acc[2][2];
  acc[0][0] = zero; acc[0][1] = zero; acc[1][0] = zero; acc[1][1] = zero;

  // T2 both-sides swizzle: pre-swizzled global source + linear LDS dest +
  // swizzled ds_read.
  const int r0 = t >> 3;
  const int sc = ((t & 7) ^ (r0 & 7)) * 8;
  const unsigned short* gA = A + (size_t)(m0 + r0) * HIDDEN + kbase + sc;
  const unsigned short* gB = Bt + (size_t)(n0 + r0) * HIDDEN + kbase + sc;
  char* lA = (char*)smem + wid * 1024;
  char* lB = (char*)smem + 16384 + wid * 1024;

#define STAGE(buf, kt)                                          \
  do {                                                          \
    const int ko = (kt)*BK;                                     \
    gload_lds16(gA + ko, lA + (buf)*8192);                      \
    gload_lds16(gA + 32 * HIDDEN + ko, lA + (buf)*8192 + 4096); \
    gload_lds16(gB + ko, lB + (buf)*8192);                      \
    gload_lds16(gB + 32 * HIDDEN + ko, lB + (buf)*8192 + 4096); \
  } while (0)

  const int row_a0 = wm + (lane & 15);
  const int row_a1 = row_a0 + 16;
  const int row_b0 = wn + (lane & 15);
  const int row_b1 = row_b0 + 16;
  const int q = lane >> 4;  // 0..3

#define COMPUTE(buf)                                                                    \
  do {                                                                                  \
    _Pragma("unroll") for (int ks = 0; ks < 2; ++ks) {                                  \
      const int cnk = ks * 4 + q;                                                       \
      bf16x8 a0 = *(const bf16x8*)&As[buf][row_a0][(cnk ^ (row_a0 & 7)) * 8];           \
      bf16x8 a1 = *(const bf16x8*)&As[buf][row_a1][(cnk ^ (row_a1 & 7)) * 8];           \
      bf16x8 b0 = *(const bf16x8*)&Bs[buf][row_b0][(cnk ^ (row_b0 & 7)) * 8];           \
      bf16x8 b1 = *(const bf16x8*)&Bs[buf][row_b1][(cnk ^ (row_b1 & 7)) * 8];           \
      acc[0][0] = __builtin_amdgcn_mfma_f32_16x16x32_bf16(a0, b0, acc[0][0], 0, 0, 0);  \
      acc[0][1] = __builtin_amdgcn_mfma_f32_16x16x32_bf16(a0, b1, acc[0][1], 0, 0, 0);  \
      acc[1][0] = __builtin_amdgcn_mfma_f32_16x16x32_bf16(a1, b0, acc[1][0], 0, 0, 0);  \
      acc[1][1] = __builtin_amdgcn_mfma_f32_16x16x32_bf16(a1, b1, acc[1][1], 0, 0, 0);  \
    }                                                                                   \
  } while (0)

  STAGE(0, 0);
  __syncthreads();
  for (int kt = 0; kt < NT; ++kt) {
    const int buf = kt & 1;
    if (kt + 1 < NT) STAGE(buf ^ 1, kt + 1);
    COMPUTE(buf);
    __syncthreads();
  }

  // Store f32 partials with agent-scope relaxed stores (LLC coherence point,
  // no cache-maintenance ops -> visible to any XCD, no fence poison).
  float* p = part + (size_t)kz * MN;
  const int rb = m0 + wm + (q << 2);
  const int cb = n0 + wn + (lane & 15);
#pragma unroll
  for (int fm = 0; fm < 2; ++fm)
#pragma unroll
    for (int fn = 0; fn < 2; ++fn)
#pragma unroll
      for (int j = 0; j < 4; ++j)
        __hip_atomic_store(&p[(size_t)(rb + fm * 16 + j) * HIDDEN + cb + fn * 16],
                           acc[fm][fn][j], __ATOMIC_RELAXED, __HIP_MEMORY_SCOPE_AGENT);
  // Stores at coherence point before the counter bump.
  asm volatile("s_waitcnt vmcnt(0)" ::: "memory");
  if (t == 0)
    s_old = __hip_atomic_fetch_add(&cnt[mt * 32 + pnl], 1u, __ATOMIC_RELAXED,
                                   __HIP_MEMORY_SCOPE_AGENT);
  __syncthreads();
  if (s_old != SPLITK - 1) return;

  // Last arriver: epilogue for this 64x64 tile. Fixed kz sum order -> deterministic.
  const int er = m0 + (t >> 2);        // 4 threads per row
  const int ec0 = n0 + (t & 3) * 16;   // 16 consecutive cols each
  const int tok = token[er];
  const float* gaterow = ihl + (size_t)tok * HIDDEN;
  const float* prevrow = prev + (size_t)er * HIDDEN;
  float s[16];
#pragma unroll
  for (int c = 0; c < 16; ++c) s[c] = 0.f;
#pragma unroll
  for (int kzi = 0; kzi < SPLITK; ++kzi) {
    const unsigned long long* src =
        (const unsigned long long*)(part + (size_t)kzi * MN + (size_t)er * HIDDEN + ec0);
#pragma unroll
    for (int u = 0; u < 8; ++u) {
      unsigned long long v =
          __hip_atomic_load(&src[u], __ATOMIC_RELAXED, __HIP_MEMORY_SCOPE_AGENT);
      s[u * 2 + 0] += __builtin_bit_cast(float, (unsigned)(v & 0xffffffffu));
      s[u * 2 + 1] += __builtin_bit_cast(float, (unsigned)(v >> 32));
    }
  }
#pragma unroll
  for (int c4 = 0; c4 < 4; ++c4) {
    float4 g = *(const float4*)(gaterow + ec0 - n0 + n0 + c4 * 4);
    float4 pv = *(const float4*)(prevrow + ec0 + c4 * 4);
    float4 r;
    r.x = tanh_fast(pv.x + s[c4 * 4 + 0] * g.x);
    r.y = tanh_fast(pv.y + s[c4 * 4 + 1] * g.y);
    r.z = tanh_fast(pv.z + s[c4 * 4 + 2] * g.z);
    r.w = tanh_fast(pv.w + s[c4 * 4 + 3] * g.w);
    *(float4*)(outf + (size_t)er * HIDDEN + ec0 + c4 * 4) = r;
    if (outb) {
      union { unsigned short h[4]; uint2 u; } o;
      o.h[0] = f2bf(r.x); o.h[1] = f2bf(r.y); o.h[2] = f2bf(r.z); o.h[3] = f2bf(r.w);
      *(uint2*)(outb + (size_t)er * HIDDEN + ec0 + c4 * 4) = o.u;
    }
  }
}

extern "C" void kernel_launch(void* const* d_in, const int* in_sizes, int n_in,
                              void* d_out, int out_size, void* d_ws, size_t ws_size,
                              hipStream_t stream) {
  const float* state = (const float*)d_in[0];
  const int* token = (const int*)d_in[1];
  const float* ih = (const float*)d_in[2];
  const float* hh = (const float*)d_in[3];
  float* out = (float*)d_out;

  // ws layout (16B-aligned):
  //   Bt   : 6*2048*2048 bf16 = 50331648 B
  //   stb  : 512*2048 bf16    =  2097152 B
  //   sf   : 512*2048 f32     =  4194304 B
  //   part : 4*512*2048 f32   = 16777216 B
  //   cnt  : 6*256 u32        =     6144 B
  char* ws = (char*)d_ws;
  unsigned short* bt = (unsigned short*)ws;
  size_t off = (size_t)NLAYERS * HIDDEN * HIDDEN * 2;
  unsigned short* stb = (unsigned short*)(ws + off);
  off += (size_t)BATCH * HIDDEN * 2;
  float* sf = (float*)(ws + off);
  off += (size_t)BATCH * HIDDEN * 4;
  float* part = (float*)(ws + off);
  off += (size_t)SPLITK * MN * 4;
  unsigned* cnt = (unsigned*)(ws + off);

  k_prep0<<<dim3(TRANS_BLOCKS + CVT_BLOCKS + NLAYERS), 256, 0, stream>>>(
      hh, bt, state, stb, cnt);

  for (int l = 0; l < NLAYERS; ++l) {
    const bool last = (l == NLAYERS - 1);
    const int nblocks = GEMM_BLOCKS + (last ? 0 : TRANS_BLOCKS);
    k_layer<<<dim3(nblocks), 256, 0, stream>>>(
        stb, bt + (size_t)l * HIDDEN * HIDDEN, part, cnt + l * NTILES,
        l == 0 ? state : sf, ih + (size_t)l * VOCAB * HIDDEN, token,
        last ? out : sf, last ? nullptr : stb,
        last ? nullptr : hh + (size_t)(l + 1) * HIDDEN * HIDDEN,
        last ? nullptr : bt + (size_t)(l + 1) * HIDDEN * HIDDEN);
  }
}

// Round 12
// 112.576 us; speedup vs baseline: 1.2446x; 1.2446x over previous
//
#include <hip/hip_runtime.h>
#include <hip/hip_bf16.h>
#include <cstdint>
#include <cstddef>

#define VOCAB 32000
#define HIDDEN 2048
#define NLAYERS 6
#define BATCH 512

#define BM 64
#define BN 64
#define BK 64
#define SPLITK 4
#define KC (HIDDEN / SPLITK)  // 512 K per block
#define NT (KC / BK)          // 8 K-tiles
#define GEMM_BLOCKS 1024
#define TRANS_BLOCKS 1024
#define CVT_BLOCKS 1024

typedef __attribute__((ext_vector_type(8))) short bf16x8;
typedef __attribute__((ext_vector_type(4))) float f32x4;

__device__ __forceinline__ unsigned short f2bf(float f) {
  unsigned u = __builtin_bit_cast(unsigned, f);
  u += 0x7fffu + ((u >> 16) & 1u);  // RNE
  return (unsigned short)(u >> 16);
}

__device__ __forceinline__ float bf2f(unsigned short h) {
  return __builtin_bit_cast(float, (unsigned)h << 16);
}

__device__ __forceinline__ float tanh_fast(float x) {
  x = fminf(15.f, fmaxf(-15.f, x));
  float e = __expf(2.f * x);
  return (e - 1.f) / (e + 1.f);
}

__device__ __forceinline__ void gload_lds16(const void* g, void* l) {
  __builtin_amdgcn_global_load_lds(
      (const __attribute__((address_space(1))) void*)g,
      (__attribute__((address_space(3))) void*)l, 16, 0, 0);
}

// ---- shared transpose tile body: hh fp32 [K][N] 64x64 tile -> bt bf16 [N][K] ----
__device__ __forceinline__ void transpose_tile(const float* __restrict__ src_layer,
                                               unsigned short* __restrict__ dst_layer,
                                               int n0, int k0, int t,
                                               unsigned short (*tile)[72]) {
  const float* src = src_layer + (size_t)k0 * HIDDEN + n0;
  const int cr = t >> 4;        // 0..15
  const int cc = (t & 15) * 4;  // 0..60
#pragma unroll
  for (int p = 0; p < 4; ++p) {
    const int r = p * 16 + cr;
    float4 v = *(const float4*)(src + (size_t)r * HIDDEN + cc);
    tile[r][cc + 0] = f2bf(v.x);
    tile[r][cc + 1] = f2bf(v.y);
    tile[r][cc + 2] = f2bf(v.z);
    tile[r][cc + 3] = f2bf(v.w);
  }
  __syncthreads();
  const int nl = t >> 2;        // output row (n), 0..63
  const int kk = (t & 3) * 16;  // k chunk
  unsigned short tmp[16] __attribute__((aligned(16)));
#pragma unroll
  for (int j = 0; j < 16; ++j) tmp[j] = tile[kk + j][nl];
  unsigned short* dst = dst_layer + (size_t)(n0 + nl) * HIDDEN + k0 + kk;
  *(uint4*)(dst) = *(const uint4*)(tmp);
  *(uint4*)(dst + 8) = *(const uint4*)(tmp + 8);
}

// ---- prep0: transpose layer 0 + cvt initial state ----
__global__ __launch_bounds__(256) void k_prep0(const float* __restrict__ hh0,
                                               unsigned short* __restrict__ bt0,
                                               const float* __restrict__ state,
                                               unsigned short* __restrict__ stb) {
  __shared__ unsigned short tile[64][72];
  const int wg = blockIdx.x;
  const int t = threadIdx.x;
  if (wg < TRANS_BLOCKS) {
    transpose_tile(hh0, bt0, (wg & 31) * 64, (wg >> 5) * 64, t, tile);
    return;
  }
  const int i = ((wg - TRANS_BLOCKS) * 256 + t) * 4;
  float4 v = *(const float4*)(state + i);
  union { unsigned short h[4]; uint2 u; } o;
  o.h[0] = f2bf(v.x); o.h[1] = f2bf(v.y); o.h[2] = f2bf(v.z); o.h[3] = f2bf(v.w);
  *(uint2*)(stb + i) = o.u;
}

// ---- combined: blocks 0..1023 = layer-l GEMM; 1024..2047 = transpose layer l+1 ----
__global__ __launch_bounds__(256, 4) void k_gemm_trans(
    const unsigned short* __restrict__ A, const unsigned short* __restrict__ Bt,
    unsigned short* __restrict__ part,
    const float* __restrict__ hhNext, unsigned short* __restrict__ btNext) {
  __shared__ __attribute__((aligned(16))) unsigned char smem[32768];
  const int t = threadIdx.x;
  const int wg = blockIdx.x;

  if (wg >= GEMM_BLOCKS) {
    const int tn = wg - GEMM_BLOCKS;
    transpose_tile(hhNext, btNext, (tn & 31) * 64, (tn >> 5) * 64, t,
                   (unsigned short(*)[72])smem);
    return;
  }

  unsigned short (*As)[BM][BK] = (unsigned short(*)[BM][BK])smem;            // [2]
  unsigned short (*Bs)[BN][BK] = (unsigned short(*)[BN][BK])(smem + 16384);  // [2]

  const int xcd = wg & 7;
  const int idx = wg >> 3;
  const int n0 = (xcd * 4 + (idx & 3)) * BN;
  const int m0 = ((idx >> 2) & 7) * BM;
  const int kz = idx >> 5;
  const int kbase = kz * KC;
  const int lane = t & 63;
  const int wid = t >> 6;
  const int wm = (wid >> 1) * 32;
  const int wn = (wid & 1) * 32;

  f32x4 zero = {0.f, 0.f, 0.f, 0.f};
  f32x4 acc[2][2];
  acc[0][0] = zero; acc[0][1] = zero; acc[1][0] = zero; acc[1][1] = zero;

  // T2 both-sides swizzle: pre-swizzled global source + linear LDS dest +
  // swizzled ds_read.
  const int r0 = t >> 3;
  const int sc = ((t & 7) ^ (r0 & 7)) * 8;
  const unsigned short* gA = A + (size_t)(m0 + r0) * HIDDEN + kbase + sc;
  const unsigned short* gB = Bt + (size_t)(n0 + r0) * HIDDEN + kbase + sc;
  char* lA = (char*)smem + wid * 1024;
  char* lB = (char*)smem + 16384 + wid * 1024;

#define STAGE(buf, kt)                                          \
  do {                                                          \
    const int ko = (kt)*BK;                                     \
    gload_lds16(gA + ko, lA + (buf)*8192);                      \
    gload_lds16(gA + 32 * HIDDEN + ko, lA + (buf)*8192 + 4096); \
    gload_lds16(gB + ko, lB + (buf)*8192);                      \
    gload_lds16(gB + 32 * HIDDEN + ko, lB + (buf)*8192 + 4096); \
  } while (0)

  const int row_a0 = wm + (lane & 15);
  const int row_a1 = row_a0 + 16;
  const int row_b0 = wn + (lane & 15);
  const int row_b1 = row_b0 + 16;
  const int q = lane >> 4;  // 0..3

#define COMPUTE(buf)                                                                    \
  do {                                                                                  \
    _Pragma("unroll") for (int ks = 0; ks < 2; ++ks) {                                  \
      const int cnk = ks * 4 + q;                                                       \
      bf16x8 a0 = *(const bf16x8*)&As[buf][row_a0][(cnk ^ (row_a0 & 7)) * 8];           \
      bf16x8 a1 = *(const bf16x8*)&As[buf][row_a1][(cnk ^ (row_a1 & 7)) * 8];           \
      bf16x8 b0 = *(const bf16x8*)&Bs[buf][row_b0][(cnk ^ (row_b0 & 7)) * 8];           \
      bf16x8 b1 = *(const bf16x8*)&Bs[buf][row_b1][(cnk ^ (row_b1 & 7)) * 8];           \
      acc[0][0] = __builtin_amdgcn_mfma_f32_16x16x32_bf16(a0, b0, acc[0][0], 0, 0, 0);  \
      acc[0][1] = __builtin_amdgcn_mfma_f32_16x16x32_bf16(a0, b1, acc[0][1], 0, 0, 0);  \
      acc[1][0] = __builtin_amdgcn_mfma_f32_16x16x32_bf16(a1, b0, acc[1][0], 0, 0, 0);  \
      acc[1][1] = __builtin_amdgcn_mfma_f32_16x16x32_bf16(a1, b1, acc[1][1], 0, 0, 0);  \
    }                                                                                   \
  } while (0)

  // Counted-vmcnt pipeline, 2 buffers, depth-1 in flight:
  //   STAGE(kt+1); vmcnt(4) [stage kt landed, kt+1 in flight]; barrier;
  //   COMPUTE(kt); lgkmcnt(0); barrier [all reads of buf^1 done -> restageable]
  STAGE(0, 0);
  for (int kt = 0; kt < NT; ++kt) {
    const int buf = kt & 1;
    if (kt + 1 < NT) {
      STAGE(buf ^ 1, kt + 1);
      asm volatile("s_waitcnt vmcnt(4)" ::: "memory");
    } else {
      asm volatile("s_waitcnt vmcnt(0)" ::: "memory");
    }
    __builtin_amdgcn_s_barrier();  // stage kt visible to all waves
    COMPUTE(buf);
    asm volatile("s_waitcnt lgkmcnt(0)" ::: "memory");
    __builtin_amdgcn_s_barrier();  // all waves done reading buf -> safe to restage
  }

  unsigned short* p = part + (size_t)kz * ((size_t)BATCH * HIDDEN);
  const int rb = m0 + wm + (q << 2);
  const int cb = n0 + wn + (lane & 15);
#pragma unroll
  for (int fm = 0; fm < 2; ++fm)
#pragma unroll
    for (int fn = 0; fn < 2; ++fn)
#pragma unroll
      for (int j = 0; j < 4; ++j)
        p[(size_t)(rb + fm * 16 + j) * HIDDEN + cb + fn * 16] = f2bf(acc[fm][fn][j]);
}

// ---- per-layer epilogue: sum bf16 split-K partials, gate, tanh ----
__global__ __launch_bounds__(256) void k_reduce(const unsigned short* __restrict__ part,
                                                const float* __restrict__ prev,
                                                const float* __restrict__ ihl,
                                                const int* __restrict__ token,
                                                float* __restrict__ outf,
                                                unsigned short* __restrict__ outb) {
  const int idx = (blockIdx.x * 256 + threadIdx.x) * 4;
  const int m = idx >> 11;
  const int n = idx & 2047;
  const size_t MN = (size_t)BATCH * HIDDEN;
  float s[4] = {0.f, 0.f, 0.f, 0.f};
#pragma unroll
  for (int kz = 0; kz < SPLITK; ++kz) {
    union { uint2 u; unsigned short h[4]; } v;
    v.u = *(const uint2*)(part + kz * MN + idx);
#pragma unroll
    for (int j = 0; j < 4; ++j) s[j] += bf2f(v.h[j]);
  }
  float4 pv = *(const float4*)(prev + idx);
  const int tok = token[m];
  float4 g = *(const float4*)(ihl + (size_t)tok * HIDDEN + n);
  float4 r;
  r.x = tanh_fast(pv.x + s[0] * g.x);
  r.y = tanh_fast(pv.y + s[1] * g.y);
  r.z = tanh_fast(pv.z + s[2] * g.z);
  r.w = tanh_fast(pv.w + s[3] * g.w);
  *(float4*)(outf + idx) = r;
  if (outb) {
    union { unsigned short h[4]; uint2 u; } o;
    o.h[0] = f2bf(r.x); o.h[1] = f2bf(r.y); o.h[2] = f2bf(r.z); o.h[3] = f2bf(r.w);
    *(uint2*)(outb + idx) = o.u;
  }
}

extern "C" void kernel_launch(void* const* d_in, const int* in_sizes, int n_in,
                              void* d_out, int out_size, void* d_ws, size_t ws_size,
                              hipStream_t stream) {
  const float* state = (const float*)d_in[0];
  const int* token = (const int*)d_in[1];
  const float* ih = (const float*)d_in[2];
  const float* hh = (const float*)d_in[3];
  float* out = (float*)d_out;

  // ws layout (16B-aligned):
  //   Bt   : 6*2048*2048 bf16 = 50331648 B
  //   stb  : 512*2048 bf16    =  2097152 B
  //   sf   : 512*2048 f32     =  4194304 B
  //   part : 4*512*2048 bf16  =  8388608 B
  char* ws = (char*)d_ws;
  unsigned short* bt = (unsigned short*)ws;
  size_t off = (size_t)NLAYERS * HIDDEN * HIDDEN * 2;
  unsigned short* stb = (unsigned short*)(ws + off);
  off += (size_t)BATCH * HIDDEN * 2;
  float* sf = (float*)(ws + off);
  off += (size_t)BATCH * HIDDEN * 4;
  unsigned short* part = (unsigned short*)(ws + off);

  k_prep0<<<dim3(TRANS_BLOCKS + CVT_BLOCKS), 256, 0, stream>>>(hh, bt, state, stb);

  for (int l = 0; l < NLAYERS; ++l) {
    const bool last = (l == NLAYERS - 1);
    const int nblocks = GEMM_BLOCKS + (last ? 0 : TRANS_BLOCKS);
    k_gemm_trans<<<dim3(nblocks), 256, 0, stream>>>(
        stb, bt + (size_t)l * HIDDEN * HIDDEN, part,
        last ? nullptr : hh + (size_t)(l + 1) * HIDDEN * HIDDEN,
        last ? nullptr : bt + (size_t)(l + 1) * HIDDEN * HIDDEN);
    k_reduce<<<dim3((BATCH * HIDDEN) / 1024), 256, 0, stream>>>(
        part, l == 0 ? state : sf, ih + (size_t)l * VOCAB * HIDDEN, token,
        last ? out : sf, last ? nullptr : stb);
  }
}